// Round 17
// baseline (90.178 us; speedup 1.0000x reference)
//
#include <hip/hip_runtime.h>
#include <cstdint>
#include <cstddef>
#include <math.h>

#define B 16
#define S 200
#define D 128
#define VOCAB 100000
#define V4 (VOCAB / 4)                 // 25000 float4 columns
#define SCH 8
#define VTILE 256                      // vocab words per v-tile
#define NVT ((VOCAB + VTILE - 1) / VTILE)    // 391 v-tiles
#define NBLK (NVT * 4)                 // 1564 blocks: (vtile, b-quarter)

// K1: attention scores: per block = one (b, chunk of 8 s). 128 threads (one per e-dim).
__global__ __launch_bounds__(128) void k_scores(
    const float* __restrict__ x,
    const float* __restrict__ Wq, const float* __restrict__ bq,
    const float* __restrict__ Wk, const float* __restrict__ bk,
    const float* __restrict__ Wv, const float* __restrict__ bv,
    float* __restrict__ scores)
{
  const int b  = blockIdx.x / (S / SCH);
  const int s0 = (blockIdx.x % (S / SCH)) * SCH;
  const int e  = threadIdx.x;

  __shared__ float lx[SCH][D];
  __shared__ float l0[D];
  __shared__ float sred[2][SCH];

  l0[e] = x[(size_t)b * S * D + e];
  #pragma unroll
  for (int i = 0; i < SCH; i++) lx[i][e] = x[((size_t)b * S + s0 + i) * D + e];
  __syncthreads();

  float q[SCH];
  const float bqe = bq[e];
  #pragma unroll
  for (int i = 0; i < SCH; i++) q[i] = bqe;
  float kk = bk[e];

  for (int d = 0; d < D; d++) {
    const float wq = Wq[d * D + e];
    const float wk = Wk[d * D + e];
    const float x0 = l0[d];
    kk += x0 * wk;
    #pragma unroll
    for (int i = 0; i < SCH; i++) q[i] += lx[i][d] * wq;
  }

  const float wv  = Wv[e];
  const float bv0 = bv[0];
  #pragma unroll
  for (int i = 0; i < SCH; i++) {
    float val = tanhf(q[i] + kk) * wv;
    #pragma unroll
    for (int off = 32; off > 0; off >>= 1) val += __shfl_down(val, off, 64);
    if ((e & 63) == 0) sred[e >> 6][i] = val;
  }
  __syncthreads();
  if (e < SCH) scores[b * S + s0 + e] = sred[0][e] + sred[1][e] + bv0;
}

// K2: softmax over S + c_s; 512 threads: 4 s-splits x 128 d.
// Writes cvec[dd*16 + b], dd 0..255 (h_t | c_s).
__global__ __launch_bounds__(512) void k_csum(
    const float* __restrict__ x, const float* __restrict__ scores,
    float* __restrict__ cvec)
{
  const int b = blockIdx.x;
  const int t = threadIdx.x;
  __shared__ float pr[S];
  __shared__ float redm[9];
  __shared__ float reds[9];
  __shared__ float cpart[3][D];

  float v = (t < S) ? scores[b * S + t] : -INFINITY;
  float m = v;
  #pragma unroll
  for (int off = 32; off > 0; off >>= 1) m = fmaxf(m, __shfl_down(m, off, 64));
  if ((t & 63) == 0) redm[t >> 6] = m;
  __syncthreads();
  if (t == 0) {
    float mm = redm[0];
    #pragma unroll
    for (int i = 1; i < 8; i++) mm = fmaxf(mm, redm[i]);
    redm[8] = mm;
  }
  __syncthreads();
  const float mx = redm[8];

  float e = (t < S) ? expf(v - mx) : 0.f;
  float s = e;
  #pragma unroll
  for (int off = 32; off > 0; off >>= 1) s += __shfl_down(s, off, 64);
  if ((t & 63) == 0) reds[t >> 6] = s;
  __syncthreads();
  if (t == 0) {
    float ss = 0.f;
    #pragma unroll
    for (int i = 0; i < 8; i++) ss += reds[i];
    reds[8] = ss;
  }
  __syncthreads();
  const float inv = 1.0f / reds[8];
  if (t < S) pr[t] = e * inv;
  __syncthreads();

  const int d = t & 127;
  const int sq = t >> 7;
  float acc = 0.f;
  const float* xb = x + ((size_t)b * S + sq * 50) * D + d;
  #pragma unroll 5
  for (int s2 = 0; s2 < 50; s2++) acc += pr[sq * 50 + s2] * xb[s2 * D];
  if (sq) cpart[sq - 1][d] = acc;
  __syncthreads();
  if (sq == 0) {
    cvec[d * B + b]       = x[(size_t)b * S * D + d];
    cvec[(D + d) * B + b] = acc + cpart[0][d] + cpart[1][d] + cpart[2][d];
  }
}

// K3: fused gemv + bias + mask + exp + per-block partial sums.
// R17 design, from the R14/R16 evidence chain:
//   - R14: reg-load batches with REGISTER-ONLY consumers stream at 23.5 TB/s;
//     R16: adding one ds_read to the consumer makes the compiler re-roll the
//     batch (VGPR=36) and serialize (~930 cy/load) with no TLP to hide it
//     (grid 391 = 1.25 blocks/CU).
//   - Fix 1: hot loop contains ONLY W loads. c is pre-loaded per-lane (lane l
//     holds c[dbase+l][bq*4..3]) and broadcast via __builtin_amdgcn_readlane
//     with literal lane indices -> SGPRs feeding v_fmac. Register-only
//     consumer, exactly the k_stream_reg shape.
//   - Fix 2: grid 391 -> 1564 (block = (vtile, b-quarter), 4 waves d-split):
//     acc is 16 VGPR, ~16 waves/CU. If the batch survives -> L3-BW-bound
//     (~400 MB at 23.5 TB/s ~= 17 us). If re-rolled -> 4 waves/SIMD of serial
//     loads still deliver ~12-15 us by TLP. Both paths beat 50 us.
__global__ __launch_bounds__(256, 3) void k_gemv(
    const float* __restrict__ cvec, const float* __restrict__ Wec,
    const float* __restrict__ bec, const int* __restrict__ ids,
    float* __restrict__ out, float* __restrict__ partial)
{
  __shared__ float4 red[4][4][65];     // [producing wave][b-idx][lane], 16.6 KB
  __shared__ unsigned mbit[4 * 8];     // this block's 4 b-rows x 256 v bits

  const int t     = threadIdx.x;
  const int lane  = t & 63;
  const int dq    = __builtin_amdgcn_readfirstlane(t >> 6);  // d-quarter wave
  const int vtile = blockIdx.x >> 2;
  const int bq    = blockIdx.x & 3;                          // b-quarter

  if (t < 32) mbit[t] = 0u;

  const int vbase = vtile * VTILE;
  const int v4    = vtile * 64 + lane;           // this thread's float4 column
  const bool valid = (v4 < V4);
  const int v4c   = valid ? v4 : (V4 - 1);
  const int dbase = dq * 64;

  const float4* wp = (const float4*)Wec + v4c;   // row stride V4

  // per-lane c: lane l holds c[dbase + l][bq*4 .. bq*4+3]  (one-time, L2-hot)
  const float4 cb4 = *(const float4*)&cvec[(dbase + lane) * 16 + bq * 4];

  // mask bitmap for this block's 4 b-rows over its 256-v range (800 ids)
  for (int i = t; i < 4 * S; i += 256) {
    const int b  = bq * 4 + i / S;
    const int id = ids[b * S + (i % S)];
    if (id > 1 && id >= vbase && id < vbase + VTILE) {
      const int lv = id - vbase;
      atomicOr(&mbit[(i / S) * 8 + (lv >> 5)], 1u << (lv & 31));
    }
  }

  float4 acc[4];     // acc[i] = b (bq*4+i), components = 4 vocab offsets
  #pragma unroll
  for (int i = 0; i < 4; i++) acc[i] = make_float4(0.f, 0.f, 0.f, 0.f);

#define BCAST(comp, sl) __int_as_float(__builtin_amdgcn_readlane(__float_as_int(comp), (sl)))

  // 4 chunks x {16 batched W loads -> register-only consumer}
  #pragma unroll
  for (int c = 0; c < 4; c++) {
    float4 w[16];
    #pragma unroll
    for (int j = 0; j < 16; j++)
      w[j] = wp[(size_t)(dbase + c * 16 + j) * V4];
    #pragma unroll
    for (int j = 0; j < 16; j++) {
      const int sl = c * 16 + j;            // literal source lane
      const float cx = BCAST(cb4.x, sl);
      const float cy = BCAST(cb4.y, sl);
      const float cz = BCAST(cb4.z, sl);
      const float cw = BCAST(cb4.w, sl);
      acc[0].x = fmaf(w[j].x, cx, acc[0].x);
      acc[0].y = fmaf(w[j].y, cx, acc[0].y);
      acc[0].z = fmaf(w[j].z, cx, acc[0].z);
      acc[0].w = fmaf(w[j].w, cx, acc[0].w);
      acc[1].x = fmaf(w[j].x, cy, acc[1].x);
      acc[1].y = fmaf(w[j].y, cy, acc[1].y);
      acc[1].z = fmaf(w[j].z, cy, acc[1].z);
      acc[1].w = fmaf(w[j].w, cy, acc[1].w);
      acc[2].x = fmaf(w[j].x, cz, acc[2].x);
      acc[2].y = fmaf(w[j].y, cz, acc[2].y);
      acc[2].z = fmaf(w[j].z, cz, acc[2].z);
      acc[2].w = fmaf(w[j].w, cz, acc[2].w);
      acc[3].x = fmaf(w[j].x, cw, acc[3].x);
      acc[3].y = fmaf(w[j].y, cw, acc[3].y);
      acc[3].z = fmaf(w[j].z, cw, acc[3].z);
      acc[3].w = fmaf(w[j].w, cw, acc[3].w);
    }
  }
#undef BCAST

  // cross-wave combine over the 4 d-quarters
  #pragma unroll
  for (int i = 0; i < 4; i++) red[dq][i][lane] = acc[i];
  __syncthreads();

  // wave dq finishes b-index i = dq  (bb = bq*4 + dq)
#define MASKED(row, lv) ((mbit[(row) * 8 + ((lv) >> 5)] >> ((lv) & 31)) & 1u)
  {
    const int bb = bq * 4 + dq;
    const float4 r0 = red[0][dq][lane], r1 = red[1][dq][lane];
    const float4 r2 = red[2][dq][lane], r3 = red[3][dq][lane];
    const float4 be4 = ((const float4*)bec)[v4c];
    const int lv0 = lane * 4;
    float4 e = make_float4(0.f, 0.f, 0.f, 0.f);
    if (valid) {
      e.x = MASKED(dq, lv0 + 0) ? 0.f : __expf(r0.x + r1.x + r2.x + r3.x + be4.x);
      e.y = MASKED(dq, lv0 + 1) ? 0.f : __expf(r0.y + r1.y + r2.y + r3.y + be4.y);
      e.z = MASKED(dq, lv0 + 2) ? 0.f : __expf(r0.z + r1.z + r2.z + r3.z + be4.z);
      e.w = MASKED(dq, lv0 + 3) ? 0.f : __expf(r0.w + r1.w + r2.w + r3.w + be4.w);
      *(float4*)&out[(size_t)bb * VOCAB + (size_t)v4 * 4] = e;
    }
    float s = e.x + e.y + e.z + e.w;
    #pragma unroll
    for (int off = 32; off > 0; off >>= 1) s += __shfl_down(s, off, 64);
    if (lane == 0) partial[vtile * 16 + bb] = s;
  }
#undef MASKED
}

// K4: normalize; each block reduces the 391 partials for its batch inline.
__global__ __launch_bounds__(256) void k_norm(float* __restrict__ out,
                                              const float* __restrict__ partial)
{
  const int b  = blockIdx.y;
  const int t  = threadIdx.x;
  __shared__ float red[4];

  float s = 0.f;
  for (int j = t; j < NVT; j += 256) s += partial[j * 16 + b];
  #pragma unroll
  for (int off = 32; off > 0; off >>= 1) s += __shfl_down(s, off, 64);
  if ((t & 63) == 0) red[t >> 6] = s;
  __syncthreads();
  const float iv = 1.0f / (red[0] + red[1] + red[2] + red[3]);

  const int i4 = blockIdx.x * 256 + t;
  if (i4 < V4) {
    float4* p = (float4*)out + (size_t)b * V4 + i4;
    float4 q = *p;
    q.x *= iv; q.y *= iv; q.z *= iv; q.w *= iv;
    *p = q;
  }
}

extern "C" void kernel_launch(void* const* d_in, const int* in_sizes, int n_in,
                              void* d_out, int out_size, void* d_ws, size_t ws_size,
                              hipStream_t stream)
{
  const float* x   = (const float*)d_in[0];
  const int*   ids = (const int*)d_in[1];
  const float* Wq  = (const float*)d_in[2];
  const float* bq  = (const float*)d_in[3];
  const float* Wk  = (const float*)d_in[4];
  const float* bk  = (const float*)d_in[5];
  const float* Wv  = (const float*)d_in[6];
  const float* bv  = (const float*)d_in[7];
  const float* Wec = (const float*)d_in[8];
  const float* bec = (const float*)d_in[9];
  float* out = (float*)d_out;
  float* ws  = (float*)d_ws;

  float* scores  = ws;            // 3200
  float* cvec    = ws + 3200;     // 4096  ([256][16])
  float* partial = ws + 7296;     // NVT*16 = 6256

  k_scores <<<dim3(B * (S / SCH)), dim3(128), 0, stream>>>(x, Wq, bq, Wk, bk, Wv, bv, scores);
  k_csum   <<<dim3(B),             dim3(512), 0, stream>>>(x, scores, cvec);
  k_gemv   <<<dim3(NBLK),          dim3(256), 0, stream>>>(cvec, Wec, bec, ids, out, partial);
  k_norm   <<<dim3((V4 + 255) / 256, B), dim3(256), 0, stream>>>(out, partial);
}

// Round 18
// 76.874 us; speedup vs baseline: 1.1731x; 1.1731x over previous
//
#include <hip/hip_runtime.h>
#include <cstdint>
#include <cstddef>
#include <math.h>

#define B 16
#define S 200
#define D 128
#define VOCAB 100000
#define V4 (VOCAB / 4)                 // 25000 float4 columns
#define SCH 8
#define VTILE 256                      // vocab words per v-tile
#define NVT ((VOCAB + VTILE - 1) / VTILE)    // 391 v-tiles

// K1: attention scores: per block = one (b, chunk of 8 s). 128 threads (one per e-dim).
__global__ __launch_bounds__(128) void k_scores(
    const float* __restrict__ x,
    const float* __restrict__ Wq, const float* __restrict__ bq,
    const float* __restrict__ Wk, const float* __restrict__ bk,
    const float* __restrict__ Wv, const float* __restrict__ bv,
    float* __restrict__ scores)
{
  const int b  = blockIdx.x / (S / SCH);
  const int s0 = (blockIdx.x % (S / SCH)) * SCH;
  const int e  = threadIdx.x;

  __shared__ float lx[SCH][D];
  __shared__ float l0[D];
  __shared__ float sred[2][SCH];

  l0[e] = x[(size_t)b * S * D + e];
  #pragma unroll
  for (int i = 0; i < SCH; i++) lx[i][e] = x[((size_t)b * S + s0 + i) * D + e];
  __syncthreads();

  float q[SCH];
  const float bqe = bq[e];
  #pragma unroll
  for (int i = 0; i < SCH; i++) q[i] = bqe;
  float kk = bk[e];

  for (int d = 0; d < D; d++) {
    const float wq = Wq[d * D + e];
    const float wk = Wk[d * D + e];
    const float x0 = l0[d];
    kk += x0 * wk;
    #pragma unroll
    for (int i = 0; i < SCH; i++) q[i] += lx[i][d] * wq;
  }

  const float wv  = Wv[e];
  const float bv0 = bv[0];
  #pragma unroll
  for (int i = 0; i < SCH; i++) {
    float val = tanhf(q[i] + kk) * wv;
    #pragma unroll
    for (int off = 32; off > 0; off >>= 1) val += __shfl_down(val, off, 64);
    if ((e & 63) == 0) sred[e >> 6][i] = val;
  }
  __syncthreads();
  if (e < SCH) scores[b * S + s0 + e] = sred[0][e] + sred[1][e] + bv0;
}

// K2: softmax over S + c_s; 512 threads: 4 s-splits x 128 d.
// Writes cvec[dd*16 + b], dd 0..255 (h_t | c_s).
__global__ __launch_bounds__(512) void k_csum(
    const float* __restrict__ x, const float* __restrict__ scores,
    float* __restrict__ cvec)
{
  const int b = blockIdx.x;
  const int t = threadIdx.x;
  __shared__ float pr[S];
  __shared__ float redm[9];
  __shared__ float reds[9];
  __shared__ float cpart[3][D];

  float v = (t < S) ? scores[b * S + t] : -INFINITY;
  float m = v;
  #pragma unroll
  for (int off = 32; off > 0; off >>= 1) m = fmaxf(m, __shfl_down(m, off, 64));
  if ((t & 63) == 0) redm[t >> 6] = m;
  __syncthreads();
  if (t == 0) {
    float mm = redm[0];
    #pragma unroll
    for (int i = 1; i < 8; i++) mm = fmaxf(mm, redm[i]);
    redm[8] = mm;
  }
  __syncthreads();
  const float mx = redm[8];

  float e = (t < S) ? expf(v - mx) : 0.f;
  float s = e;
  #pragma unroll
  for (int off = 32; off > 0; off >>= 1) s += __shfl_down(s, off, 64);
  if ((t & 63) == 0) reds[t >> 6] = s;
  __syncthreads();
  if (t == 0) {
    float ss = 0.f;
    #pragma unroll
    for (int i = 0; i < 8; i++) ss += reds[i];
    reds[8] = ss;
  }
  __syncthreads();
  const float inv = 1.0f / reds[8];
  if (t < S) pr[t] = e * inv;
  __syncthreads();

  const int d = t & 127;
  const int sq = t >> 7;
  float acc = 0.f;
  const float* xb = x + ((size_t)b * S + sq * 50) * D + d;
  #pragma unroll 5
  for (int s2 = 0; s2 < 50; s2++) acc += pr[sq * 50 + s2] * xb[s2 * D];
  if (sq) cpart[sq - 1][d] = acc;
  __syncthreads();
  if (sq == 0) {
    cvec[d * B + b]       = x[(size_t)b * S * D + d];
    cvec[(D + d) * B + b] = acc + cpart[0][d] + cpart[1][d] + cpart[2][d];
  }
}

// K3: fused gemv + bias + mask + exp + per-block partial sums.
// R18 "16-wave block" design, from the R16/R17 occupancy scaling law
// (~227 GB/s per wave/CU with the compiler's serial loads):
//   - ONE 1024-thread block per v-tile: 16 waves = 4 d-quarters x 4
//     b-quarters. Wave (dq,bq): thread = 1 float4 col x 4 b x 64 d,
//     acc = 16 VGPR. Hot loop identical to R17 (W loads + literal readlane
//     broadcasts + FMA; register-only consumer).
//   - HBM traffic 1x (102 MB): the 4 bq waves re-read the same W tile via
//     L2 (400 MB L2 at 34.5 TB/s = cheap); R17's 4x HBM FETCH (200 GB) gone.
//   - __launch_bounds__(1024, 8): VGPR cap 64 -> 2 blocks/CU co-resident
//     (LDS 67 KB x 2 = 134 <= 160 KB) -> up to 32 waves/CU of TLP.
//   - In-block d-combine via LDS; zero cross-block reduction.
__global__ __launch_bounds__(1024, 8) void k_gemv(
    const float* __restrict__ cvec, const float* __restrict__ Wec,
    const float* __restrict__ bec, const int* __restrict__ ids,
    float* __restrict__ out, float* __restrict__ partial)
{
  __shared__ float4 red[4][4][4][65];  // [bq][producing dq][b-idx][lane], 66.5 KB
  __shared__ unsigned mbit[B * 8];     // 16 b x 256 v bits

  const int t    = threadIdx.x;
  const int lane = t & 63;
  const int wv   = __builtin_amdgcn_readfirstlane(t >> 6);   // wave id 0..15
  const int dq   = wv & 3;                                   // d-quarter
  const int bq   = wv >> 2;                                  // b-quarter

  if (t < B * 8) mbit[t] = 0u;

  const int vtile = blockIdx.x;
  const int vbase = vtile * VTILE;
  const int v4    = vtile * 64 + lane;           // this thread's float4 column
  const bool valid = (v4 < V4);
  const int v4c   = valid ? v4 : (V4 - 1);
  const int dbase = dq * 64;

  const float4* wp = (const float4*)Wec + v4c;   // row stride V4

  // per-lane c: lane l holds c[dbase + l][bq*4 .. bq*4+3]  (one-time, L2-hot)
  const float4 cb4 = *(const float4*)&cvec[(dbase + lane) * 16 + bq * 4];

  // mask bitmap over all 16 b for this v-range (3200 ids, ~3 iters/thread)
  for (int i = t; i < B * S; i += 1024) {
    const int id = ids[i];
    if (id > 1 && id >= vbase && id < vbase + VTILE) {
      const int lv = id - vbase;
      atomicOr(&mbit[(i / S) * 8 + (lv >> 5)], 1u << (lv & 31));
    }
  }

  float4 acc[4];     // acc[i] = b (bq*4+i), components = 4 vocab offsets
  #pragma unroll
  for (int i = 0; i < 4; i++) acc[i] = make_float4(0.f, 0.f, 0.f, 0.f);

#define BCAST(comp, sl) __int_as_float(__builtin_amdgcn_readlane(__float_as_int(comp), (sl)))

  // 4 chunks x {16 W loads -> register-only consumer}
  #pragma unroll
  for (int c = 0; c < 4; c++) {
    float4 w[16];
    #pragma unroll
    for (int j = 0; j < 16; j++)
      w[j] = wp[(size_t)(dbase + c * 16 + j) * V4];
    #pragma unroll
    for (int j = 0; j < 16; j++) {
      const int sl = c * 16 + j;            // literal source lane
      const float cx = BCAST(cb4.x, sl);
      const float cy = BCAST(cb4.y, sl);
      const float cz = BCAST(cb4.z, sl);
      const float cw = BCAST(cb4.w, sl);
      acc[0].x = fmaf(w[j].x, cx, acc[0].x);
      acc[0].y = fmaf(w[j].y, cx, acc[0].y);
      acc[0].z = fmaf(w[j].z, cx, acc[0].z);
      acc[0].w = fmaf(w[j].w, cx, acc[0].w);
      acc[1].x = fmaf(w[j].x, cy, acc[1].x);
      acc[1].y = fmaf(w[j].y, cy, acc[1].y);
      acc[1].z = fmaf(w[j].z, cy, acc[1].z);
      acc[1].w = fmaf(w[j].w, cy, acc[1].w);
      acc[2].x = fmaf(w[j].x, cz, acc[2].x);
      acc[2].y = fmaf(w[j].y, cz, acc[2].y);
      acc[2].z = fmaf(w[j].z, cz, acc[2].z);
      acc[2].w = fmaf(w[j].w, cz, acc[2].w);
      acc[3].x = fmaf(w[j].x, cw, acc[3].x);
      acc[3].y = fmaf(w[j].y, cw, acc[3].y);
      acc[3].z = fmaf(w[j].z, cw, acc[3].z);
      acc[3].w = fmaf(w[j].w, cw, acc[3].w);
    }
  }
#undef BCAST

  // cross-wave combine over the 4 d-quarters (within each bq group)
  #pragma unroll
  for (int i = 0; i < 4; i++) red[bq][dq][i][lane] = acc[i];
  __syncthreads();

  // wave (bq,dq) finishes bb = bq*4 + dq
#define MASKED(bb, lv) ((mbit[(bb) * 8 + ((lv) >> 5)] >> ((lv) & 31)) & 1u)
  {
    const int bb = bq * 4 + dq;
    const float4 r0 = red[bq][0][dq][lane], r1 = red[bq][1][dq][lane];
    const float4 r2 = red[bq][2][dq][lane], r3 = red[bq][3][dq][lane];
    const float4 be4 = ((const float4*)bec)[v4c];
    const int lv0 = lane * 4;
    float4 e = make_float4(0.f, 0.f, 0.f, 0.f);
    if (valid) {
      e.x = MASKED(bb, lv0 + 0) ? 0.f : __expf(r0.x + r1.x + r2.x + r3.x + be4.x);
      e.y = MASKED(bb, lv0 + 1) ? 0.f : __expf(r0.y + r1.y + r2.y + r3.y + be4.y);
      e.z = MASKED(bb, lv0 + 2) ? 0.f : __expf(r0.z + r1.z + r2.z + r3.z + be4.z);
      e.w = MASKED(bb, lv0 + 3) ? 0.f : __expf(r0.w + r1.w + r2.w + r3.w + be4.w);
      *(float4*)&out[(size_t)bb * VOCAB + (size_t)v4 * 4] = e;
    }
    float s = e.x + e.y + e.z + e.w;
    #pragma unroll
    for (int off = 32; off > 0; off >>= 1) s += __shfl_down(s, off, 64);
    if (lane == 0) partial[vtile * 16 + bb] = s;
  }
#undef MASKED
}

// K4: normalize; each block reduces the 391 partials for its batch inline.
__global__ __launch_bounds__(256) void k_norm(float* __restrict__ out,
                                              const float* __restrict__ partial)
{
  const int b  = blockIdx.y;
  const int t  = threadIdx.x;
  __shared__ float red[4];

  float s = 0.f;
  for (int j = t; j < NVT; j += 256) s += partial[j * 16 + b];
  #pragma unroll
  for (int off = 32; off > 0; off >>= 1) s += __shfl_down(s, off, 64);
  if ((t & 63) == 0) red[t >> 6] = s;
  __syncthreads();
  const float iv = 1.0f / (red[0] + red[1] + red[2] + red[3]);

  const int i4 = blockIdx.x * 256 + t;
  if (i4 < V4) {
    float4* p = (float4*)out + (size_t)b * V4 + i4;
    float4 q = *p;
    q.x *= iv; q.y *= iv; q.z *= iv; q.w *= iv;
    *p = q;
  }
}

extern "C" void kernel_launch(void* const* d_in, const int* in_sizes, int n_in,
                              void* d_out, int out_size, void* d_ws, size_t ws_size,
                              hipStream_t stream)
{
  const float* x   = (const float*)d_in[0];
  const int*   ids = (const int*)d_in[1];
  const float* Wq  = (const float*)d_in[2];
  const float* bq  = (const float*)d_in[3];
  const float* Wk  = (const float*)d_in[4];
  const float* bk  = (const float*)d_in[5];
  const float* Wv  = (const float*)d_in[6];
  const float* bv  = (const float*)d_in[7];
  const float* Wec = (const float*)d_in[8];
  const float* bec = (const float*)d_in[9];
  float* out = (float*)d_out;
  float* ws  = (float*)d_ws;

  float* scores  = ws;            // 3200
  float* cvec    = ws + 3200;     // 4096  ([256][16])
  float* partial = ws + 7296;     // NVT*16 = 6256

  k_scores <<<dim3(B * (S / SCH)), dim3(128), 0, stream>>>(x, Wq, bq, Wk, bk, Wv, bv, scores);
  k_csum   <<<dim3(B),             dim3(512), 0, stream>>>(x, scores, cvec);
  k_gemv   <<<dim3(NVT),           dim3(1024), 0, stream>>>(cvec, Wec, bec, ids, out, partial);
  k_norm   <<<dim3((V4 + 255) / 256, B), dim3(256), 0, stream>>>(out, partial);
}

// Round 20
// 64.187 us; speedup vs baseline: 1.4049x; 1.1977x over previous
//
#include <hip/hip_runtime.h>
#include <cstdint>
#include <cstddef>
#include <math.h>

#define B 16
#define S 200
#define D 128
#define VOCAB 100000
#define V4 (VOCAB / 4)                 // 25000 float4 columns
#define SCH 8
#define VTILE 256                      // vocab words per v-tile
#define NVT ((VOCAB + VTILE - 1) / VTILE)    // 391 v-tiles

// K1: attention scores: per block = one (b, chunk of 8 s). 128 threads (one per e-dim).
__global__ __launch_bounds__(128) void k_scores(
    const float* __restrict__ x,
    const float* __restrict__ Wq, const float* __restrict__ bq,
    const float* __restrict__ Wk, const float* __restrict__ bk,
    const float* __restrict__ Wv, const float* __restrict__ bv,
    float* __restrict__ scores)
{
  const int b  = blockIdx.x / (S / SCH);
  const int s0 = (blockIdx.x % (S / SCH)) * SCH;
  const int e  = threadIdx.x;

  __shared__ float lx[SCH][D];
  __shared__ float l0[D];
  __shared__ float sred[2][SCH];

  l0[e] = x[(size_t)b * S * D + e];
  #pragma unroll
  for (int i = 0; i < SCH; i++) lx[i][e] = x[((size_t)b * S + s0 + i) * D + e];
  __syncthreads();

  float q[SCH];
  const float bqe = bq[e];
  #pragma unroll
  for (int i = 0; i < SCH; i++) q[i] = bqe;
  float kk = bk[e];

  for (int d = 0; d < D; d++) {
    const float wq = Wq[d * D + e];
    const float wk = Wk[d * D + e];
    const float x0 = l0[d];
    kk += x0 * wk;
    #pragma unroll
    for (int i = 0; i < SCH; i++) q[i] += lx[i][d] * wq;
  }

  const float wv  = Wv[e];
  const float bv0 = bv[0];
  #pragma unroll
  for (int i = 0; i < SCH; i++) {
    float val = tanhf(q[i] + kk) * wv;
    #pragma unroll
    for (int off = 32; off > 0; off >>= 1) val += __shfl_down(val, off, 64);
    if ((e & 63) == 0) sred[e >> 6][i] = val;
  }
  __syncthreads();
  if (e < SCH) scores[b * S + s0 + e] = sred[0][e] + sred[1][e] + bv0;
}

// K2: softmax over S + c_s; 512 threads: 4 s-splits x 128 d.
// Writes cvec[dd*16 + b], dd 0..255 (h_t | c_s).
__global__ __launch_bounds__(512) void k_csum(
    const float* __restrict__ x, const float* __restrict__ scores,
    float* __restrict__ cvec)
{
  const int b = blockIdx.x;
  const int t = threadIdx.x;
  __shared__ float pr[S];
  __shared__ float redm[9];
  __shared__ float reds[9];
  __shared__ float cpart[3][D];

  float v = (t < S) ? scores[b * S + t] : -INFINITY;
  float m = v;
  #pragma unroll
  for (int off = 32; off > 0; off >>= 1) m = fmaxf(m, __shfl_down(m, off, 64));
  if ((t & 63) == 0) redm[t >> 6] = m;
  __syncthreads();
  if (t == 0) {
    float mm = redm[0];
    #pragma unroll
    for (int i = 1; i < 8; i++) mm = fmaxf(mm, redm[i]);
    redm[8] = mm;
  }
  __syncthreads();
  const float mx = redm[8];

  float e = (t < S) ? expf(v - mx) : 0.f;
  float s = e;
  #pragma unroll
  for (int off = 32; off > 0; off >>= 1) s += __shfl_down(s, off, 64);
  if ((t & 63) == 0) reds[t >> 6] = s;
  __syncthreads();
  if (t == 0) {
    float ss = 0.f;
    #pragma unroll
    for (int i = 0; i < 8; i++) ss += reds[i];
    reds[8] = ss;
  }
  __syncthreads();
  const float inv = 1.0f / reds[8];
  if (t < S) pr[t] = e * inv;
  __syncthreads();

  const int d = t & 127;
  const int sq = t >> 7;
  float acc = 0.f;
  const float* xb = x + ((size_t)b * S + sq * 50) * D + d;
  #pragma unroll 5
  for (int s2 = 0; s2 < 50; s2++) acc += pr[sq * 50 + s2] * xb[s2 * D];
  if (sq) cpart[sq - 1][d] = acc;
  __syncthreads();
  if (sq == 0) {
    cvec[d * B + b]       = x[(size_t)b * S * D + d];
    cvec[(D + d) * B + b] = acc + cpart[0][d] + cpart[1][d] + cpart[2][d];
  }
}

// K3: fused gemv + bias + mask + exp + per-block partial sums.
// R20 = R19 with the macro-parameter/member-token collision fixed (param `w`
// shadowed the `.w` member; renamed to `Wv`). Design unchanged:
//   - Block = 1024 threads = 16 waves = 16 d-sixteenths; thread = 1 float4
//     column x 16 d x ALL 16 b -> logical traffic 1x (102 MB).
//   - acc[16] float4 = 64 VGPR; c via per-lane preload + literal-lane
//     readlane broadcasts; hot loop = W loads + register-only consumer.
//   - Combine: 4 rounds through 64 KB LDS; fused bias/mask/exp/store/psum.
__global__ __launch_bounds__(1024, 4) void k_gemv(
    const float* __restrict__ cvec, const float* __restrict__ Wec,
    const float* __restrict__ bec, const int* __restrict__ ids,
    float* __restrict__ out, float* __restrict__ partial)
{
  __shared__ float4 cbuf[16][4][64];   // 64 KB combine buffer
  __shared__ unsigned mbit[B * 8];     // 16 b x 256 v bits

  const int t    = threadIdx.x;
  const int lane = t & 63;
  const int wv   = __builtin_amdgcn_readfirstlane(t >> 6);  // d-sixteenth 0..15

  if (t < B * 8) mbit[t] = 0u;
  __syncthreads();     // init visible before any atomicOr

  const int vtile = blockIdx.x;
  const int vbase = vtile * VTILE;
  const int v4    = vtile * 64 + lane;           // this thread's float4 column
  const bool valid = (v4 < V4);
  const int v4c   = valid ? v4 : (V4 - 1);
  const int dbase = wv * 16;

  const float4* wp = (const float4*)Wec + v4c;   // row stride V4

  // per-lane c: lane l holds cvec[wv*256 + l*4 .. +3]
  // (= rows [wv*16, wv*16+16) x 16 b, flat [d][b]); row j of the slice
  // lives on lanes j*4..j*4+3 (4 consecutive b per lane).
  const float4 creg = *(const float4*)&cvec[wv * 256 + lane * 4];

  // mask bitmap over all 16 b for this v-range
  for (int i = t; i < B * S; i += 1024) {
    const int id = ids[i];
    if (id > 1 && id >= vbase && id < vbase + VTILE) {
      const int lv = id - vbase;
      atomicOr(&mbit[(i / S) * 8 + (lv >> 5)], 1u << (lv & 31));
    }
  }

  float4 acc[16];    // acc[bb], components = 4 vocab offsets
  #pragma unroll
  for (int i = 0; i < 16; i++) acc[i] = make_float4(0.f, 0.f, 0.f, 0.f);

#define RL(comp, sl) __int_as_float(__builtin_amdgcn_readlane(__float_as_int(comp), (sl)))

#define CONSUME(Wv, j)                                                     \
  { const float c0x = RL(creg.x, (j) * 4 + 0), c0y = RL(creg.y, (j) * 4 + 0); \
    const float c0z = RL(creg.z, (j) * 4 + 0), c0w = RL(creg.w, (j) * 4 + 0); \
    const float c1x = RL(creg.x, (j) * 4 + 1), c1y = RL(creg.y, (j) * 4 + 1); \
    const float c1z = RL(creg.z, (j) * 4 + 1), c1w = RL(creg.w, (j) * 4 + 1); \
    const float c2x = RL(creg.x, (j) * 4 + 2), c2y = RL(creg.y, (j) * 4 + 2); \
    const float c2z = RL(creg.z, (j) * 4 + 2), c2w = RL(creg.w, (j) * 4 + 2); \
    const float c3x = RL(creg.x, (j) * 4 + 3), c3y = RL(creg.y, (j) * 4 + 3); \
    const float c3z = RL(creg.z, (j) * 4 + 3), c3w = RL(creg.w, (j) * 4 + 3); \
    acc[0].x  = fmaf(Wv.x, c0x, acc[0].x);  acc[0].y  = fmaf(Wv.y, c0x, acc[0].y);  \
    acc[0].z  = fmaf(Wv.z, c0x, acc[0].z);  acc[0].w  = fmaf(Wv.w, c0x, acc[0].w);  \
    acc[1].x  = fmaf(Wv.x, c0y, acc[1].x);  acc[1].y  = fmaf(Wv.y, c0y, acc[1].y);  \
    acc[1].z  = fmaf(Wv.z, c0y, acc[1].z);  acc[1].w  = fmaf(Wv.w, c0y, acc[1].w);  \
    acc[2].x  = fmaf(Wv.x, c0z, acc[2].x);  acc[2].y  = fmaf(Wv.y, c0z, acc[2].y);  \
    acc[2].z  = fmaf(Wv.z, c0z, acc[2].z);  acc[2].w  = fmaf(Wv.w, c0z, acc[2].w);  \
    acc[3].x  = fmaf(Wv.x, c0w, acc[3].x);  acc[3].y  = fmaf(Wv.y, c0w, acc[3].y);  \
    acc[3].z  = fmaf(Wv.z, c0w, acc[3].z);  acc[3].w  = fmaf(Wv.w, c0w, acc[3].w);  \
    acc[4].x  = fmaf(Wv.x, c1x, acc[4].x);  acc[4].y  = fmaf(Wv.y, c1x, acc[4].y);  \
    acc[4].z  = fmaf(Wv.z, c1x, acc[4].z);  acc[4].w  = fmaf(Wv.w, c1x, acc[4].w);  \
    acc[5].x  = fmaf(Wv.x, c1y, acc[5].x);  acc[5].y  = fmaf(Wv.y, c1y, acc[5].y);  \
    acc[5].z  = fmaf(Wv.z, c1y, acc[5].z);  acc[5].w  = fmaf(Wv.w, c1y, acc[5].w);  \
    acc[6].x  = fmaf(Wv.x, c1z, acc[6].x);  acc[6].y  = fmaf(Wv.y, c1z, acc[6].y);  \
    acc[6].z  = fmaf(Wv.z, c1z, acc[6].z);  acc[6].w  = fmaf(Wv.w, c1z, acc[6].w);  \
    acc[7].x  = fmaf(Wv.x, c1w, acc[7].x);  acc[7].y  = fmaf(Wv.y, c1w, acc[7].y);  \
    acc[7].z  = fmaf(Wv.z, c1w, acc[7].z);  acc[7].w  = fmaf(Wv.w, c1w, acc[7].w);  \
    acc[8].x  = fmaf(Wv.x, c2x, acc[8].x);  acc[8].y  = fmaf(Wv.y, c2x, acc[8].y);  \
    acc[8].z  = fmaf(Wv.z, c2x, acc[8].z);  acc[8].w  = fmaf(Wv.w, c2x, acc[8].w);  \
    acc[9].x  = fmaf(Wv.x, c2y, acc[9].x);  acc[9].y  = fmaf(Wv.y, c2y, acc[9].y);  \
    acc[9].z  = fmaf(Wv.z, c2y, acc[9].z);  acc[9].w  = fmaf(Wv.w, c2y, acc[9].w);  \
    acc[10].x = fmaf(Wv.x, c2z, acc[10].x); acc[10].y = fmaf(Wv.y, c2z, acc[10].y); \
    acc[10].z = fmaf(Wv.z, c2z, acc[10].z); acc[10].w = fmaf(Wv.w, c2z, acc[10].w); \
    acc[11].x = fmaf(Wv.x, c2w, acc[11].x); acc[11].y = fmaf(Wv.y, c2w, acc[11].y); \
    acc[11].z = fmaf(Wv.z, c2w, acc[11].z); acc[11].w = fmaf(Wv.w, c2w, acc[11].w); \
    acc[12].x = fmaf(Wv.x, c3x, acc[12].x); acc[12].y = fmaf(Wv.y, c3x, acc[12].y); \
    acc[12].z = fmaf(Wv.z, c3x, acc[12].z); acc[12].w = fmaf(Wv.w, c3x, acc[12].w); \
    acc[13].x = fmaf(Wv.x, c3y, acc[13].x); acc[13].y = fmaf(Wv.y, c3y, acc[13].y); \
    acc[13].z = fmaf(Wv.z, c3y, acc[13].z); acc[13].w = fmaf(Wv.w, c3y, acc[13].w); \
    acc[14].x = fmaf(Wv.x, c3z, acc[14].x); acc[14].y = fmaf(Wv.y, c3z, acc[14].y); \
    acc[14].z = fmaf(Wv.z, c3z, acc[14].z); acc[14].w = fmaf(Wv.w, c3z, acc[14].w); \
    acc[15].x = fmaf(Wv.x, c3w, acc[15].x); acc[15].y = fmaf(Wv.y, c3w, acc[15].y); \
    acc[15].z = fmaf(Wv.z, c3w, acc[15].z); acc[15].w = fmaf(Wv.w, c3w, acc[15].w); }

  // 8 pairs of rows; both loads issued before either consumer
  #pragma unroll
  for (int jj = 0; jj < 16; jj += 2) {
    const float4 w0 = wp[(size_t)(dbase + jj) * V4];
    const float4 w1 = wp[(size_t)(dbase + jj + 1) * V4];
    CONSUME(w0, jj)
    CONSUME(w1, jj + 1)
  }
#undef CONSUME
#undef RL

  // combine: 4 rounds of 4 b each
#define MASKED(bb, lv) ((mbit[(bb) * 8 + ((lv) >> 5)] >> ((lv) & 31)) & 1u)
  const float4 be4 = ((const float4*)bec)[v4c];
  const int lv0 = lane * 4;

  #pragma unroll
  for (int r = 0; r < 4; r++) {
    __syncthreads();               // prev round consumed (and mbit on r=0)
    #pragma unroll
    for (int i = 0; i < 4; i++) cbuf[wv][i][lane] = acc[r * 4 + i];
    __syncthreads();
    if (wv < 4) {
      const int bb = r * 4 + wv;
      float4 s = cbuf[0][wv][lane];
      #pragma unroll
      for (int sw = 1; sw < 16; sw++) {
        const float4 q = cbuf[sw][wv][lane];
        s.x += q.x; s.y += q.y; s.z += q.z; s.w += q.w;
      }
      float4 e = make_float4(0.f, 0.f, 0.f, 0.f);
      if (valid) {
        e.x = MASKED(bb, lv0 + 0) ? 0.f : __expf(s.x + be4.x);
        e.y = MASKED(bb, lv0 + 1) ? 0.f : __expf(s.y + be4.y);
        e.z = MASKED(bb, lv0 + 2) ? 0.f : __expf(s.z + be4.z);
        e.w = MASKED(bb, lv0 + 3) ? 0.f : __expf(s.w + be4.w);
        *(float4*)&out[(size_t)bb * VOCAB + (size_t)v4 * 4] = e;
      }
      float ps = e.x + e.y + e.z + e.w;
      #pragma unroll
      for (int off = 32; off > 0; off >>= 1) ps += __shfl_down(ps, off, 64);
      if (lane == 0) partial[vtile * 16 + bb] = ps;
    }
  }
#undef MASKED
}

// K4: normalize; each block reduces the 391 partials for its batch inline.
__global__ __launch_bounds__(256) void k_norm(float* __restrict__ out,
                                              const float* __restrict__ partial)
{
  const int b  = blockIdx.y;
  const int t  = threadIdx.x;
  __shared__ float red[4];

  float s = 0.f;
  for (int j = t; j < NVT; j += 256) s += partial[j * 16 + b];
  #pragma unroll
  for (int off = 32; off > 0; off >>= 1) s += __shfl_down(s, off, 64);
  if ((t & 63) == 0) red[t >> 6] = s;
  __syncthreads();
  const float iv = 1.0f / (red[0] + red[1] + red[2] + red[3]);

  const int i4 = blockIdx.x * 256 + t;
  if (i4 < V4) {
    float4* p = (float4*)out + (size_t)b * V4 + i4;
    float4 q = *p;
    q.x *= iv; q.y *= iv; q.z *= iv; q.w *= iv;
    *p = q;
  }
}

extern "C" void kernel_launch(void* const* d_in, const int* in_sizes, int n_in,
                              void* d_out, int out_size, void* d_ws, size_t ws_size,
                              hipStream_t stream)
{
  const float* x   = (const float*)d_in[0];
  const int*   ids = (const int*)d_in[1];
  const float* Wq  = (const float*)d_in[2];
  const float* bq  = (const float*)d_in[3];
  const float* Wk  = (const float*)d_in[4];
  const float* bk  = (const float*)d_in[5];
  const float* Wv  = (const float*)d_in[6];
  const float* bv  = (const float*)d_in[7];
  const float* Wec = (const float*)d_in[8];
  const float* bec = (const float*)d_in[9];
  float* out = (float*)d_out;
  float* ws  = (float*)d_ws;

  float* scores  = ws;            // 3200
  float* cvec    = ws + 3200;     // 4096  ([256][16])
  float* partial = ws + 7296;     // NVT*16 = 6256

  k_scores <<<dim3(B * (S / SCH)), dim3(128), 0, stream>>>(x, Wq, bq, Wk, bk, Wv, bv, scores);
  k_csum   <<<dim3(B),             dim3(512), 0, stream>>>(x, scores, cvec);
  k_gemv   <<<dim3(NVT),           dim3(1024), 0, stream>>>(cvec, Wec, bec, ids, out, partial);
  k_norm   <<<dim3((V4 + 255) / 256, B), dim3(256), 0, stream>>>(out, partial);
}